// Round 10
// baseline (92.270 us; speedup 1.0000x reference)
//
#include <hip/hip_runtime.h>

// NW kernel regression, fused pairwise evaluation.
// queries [N,3] f32, keys [M,3] f32, values [M,8] f32, kernelLen [1] f32
// out [N,8] f32 = (K @ V) / (K @ 1) + 1e-6,
// K[i,j] = max(0, (2+cos(2*pi*d))*(1-d)/3 + sin(2*pi*d)/(2*pi)), d = |q_i-k_j|/L
//
// Round-10: k/v via VECTOR global loads (vmcnt) instead of readfirstlane/s_load.
// Round 9 evidence: s_load(k/v) + ds_read(LUT) both use lgkmcnt and complete
// out-of-order -> compiler emits lgkmcnt(0) before every LUT consume -> ~13us
// stall at 68.6% VALUBusy. Splitting k/v onto vmcnt leaves the LUT as the only
// lgkm consumer -> fine-grained waits, stalls hidden by occupancy.
//  - weight via nearest-neighbor 4096-cell LUT in s=(d/L)^2 domain (C4-flat at
//    clamp; quantization ~1e-4 output err, absmax 4.9e-4 vs 2e-3 threshold)
//  - v2f packed accumulation (v_pk_fma_f32)
//  - deterministic partials in d_ws + reduce kernel

typedef float v2f __attribute__((ext_vector_type(2)));

#define NCH 8
#define QG 64          // queries per block (= lanes per wave)
#define KSB 512        // keys per block
#define TPB 512        // threads per block
#define NWAVE 8
#define KPW (KSB / NWAVE)   // keys per wave = 64
#define LUTN 4096

__device__ __forceinline__ float nw_weight_exact(float cd) {
    float r  = __builtin_amdgcn_fractf(cd);
    float sn = __builtin_amdgcn_sinf(r);
    float cs = __builtin_amdgcn_cosf(r);
    float t  = (1.0f - cd) * (1.0f / 3.0f);
    float wt = fmaf(sn, 0.15915494309189535f, fmaf(cs, t, t + t));
    return fmaxf(wt, 0.0f);
}

__global__ __launch_bounds__(TPB) void nw_main(const float* __restrict__ q,
                                               const float* __restrict__ k,
                                               const float* __restrict__ v,
                                               const float* __restrict__ kl,
                                               float* __restrict__ part,
                                               int N) {
    __shared__ float lutw[LUTN + 1];   // w at s = e/LUTN
    __shared__ float red[TPB * 10];    // cross-wave reduce buffer

    const int tid  = threadIdx.x;
    const int lane = tid & 63;
    const int wid  = tid >> 6;         // stays VGPR -> k/v loads stay vector (vmcnt)
    const int qg   = blockIdx.x;
    const int sb   = blockIdx.y;

    const float invL = 1.0f / kl[0];

    // ---- build LUT over s in [0,1] (4097 exact evals, amortized) ----
    for (int e = tid; e <= LUTN; e += TPB) {
        float s = (float)e * (1.0f / (float)LUTN);
        lutw[e] = nw_weight_exact(__builtin_amdgcn_sqrtf(s));
    }
    __syncthreads();

    const int i = qg * QG + lane;
    const float qx = q[i * 3 + 0];
    const float qy = q[i * 3 + 1];
    const float qz = q[i * 3 + 2];
    const float scale = invL * invL * (float)LUTN;

    const int jbase = sb * KSB + wid * KPW;
    const float* __restrict__ kp = k + (size_t)jbase * 3;
    const float* __restrict__ vp = v + (size_t)jbase * 8;

    v2f acc4[4];
#pragma unroll
    for (int c = 0; c < 4; ++c) acc4[c] = v2f{0.0f, 0.0f};
    float den = 0.0f;

#pragma unroll 8
    for (int jj = 0; jj < KPW; ++jj) {
        // vector global loads (uniform addr -> hardware broadcast, L1/L2 hot),
        // tracked by vmcnt: independent of the LUT's lgkmcnt
        const float kx = kp[jj * 3 + 0];
        const float ky = kp[jj * 3 + 1];
        const float kz = kp[jj * 3 + 2];
        const v2f* vv = (const v2f*)(vp + (size_t)jj * 8);
        const v2f v0 = vv[0], v1 = vv[1], v2 = vv[2], v3 = vv[3];

        float dx = qx - kx, dy = qy - ky, dz = qz - kz;
        float d2 = fmaf(dx, dx, fmaf(dy, dy, dz * dz));
        float fidx = fminf(fmaf(d2, scale, 0.5f), (float)LUTN);  // round + clamp
        int   idx  = (int)fidx;
        float wt   = lutw[idx];                   // only lgkm op in the loop

        den += wt;
        v2f w2; w2.x = wt; w2.y = wt;
        acc4[0] += w2 * v0;                       // v_pk_fma_f32
        acc4[1] += w2 * v1;
        acc4[2] += w2 * v2;
        acc4[3] += w2 * v3;
    }

    __syncthreads();   // LUT phase over; red[] free
    {
        float vals[10] = {acc4[0].x, acc4[0].y, acc4[1].x, acc4[1].y,
                          acc4[2].x, acc4[2].y, acc4[3].x, acc4[3].y, den, 0.0f};
        float* r = red + (size_t)(wid * 64 + lane) * 10;
#pragma unroll
        for (int c = 0; c < 10; ++c) r[c] = vals[c];
    }
    __syncthreads();

    // cross-wave sum: thread (c=wid, l=lane) -> part[sb][c][qg*64+l]
    {
        const int c = wid, l = lane;
        float s = 0.0f;
#pragma unroll
        for (int ww = 0; ww < NWAVE; ++ww) s += red[(size_t)(ww * 64 + l) * 10 + c];
        const int gi = qg * QG + l;
        part[((size_t)sb * 10 + c) * N + gi] = s;
        if (tid < 64) {
            float sd = 0.0f;
#pragma unroll
            for (int ww = 0; ww < NWAVE; ++ww) sd += red[(size_t)(ww * 64 + l) * 10 + 8];
            part[((size_t)sb * 10 + 8) * N + gi] = sd;
        }
    }
}

// out[i,c] = (sum_sb num) / (sum_sb den) + 1e-6; coalesced row reads
__global__ __launch_bounds__(256) void nw_reduce(const float* __restrict__ part,
                                                 float* __restrict__ out,
                                                 int N, int nsb) {
    const int i = blockIdx.x * 256 + threadIdx.x;
    if (i >= N) return;
    float o[NCH];
#pragma unroll
    for (int c = 0; c < NCH; ++c) o[c] = 0.0f;
    float den = 0.0f;
    for (int sb = 0; sb < nsb; ++sb) {
        const float* base = part + (size_t)sb * 10 * N + i;
        den += base[8 * (size_t)N];
#pragma unroll
        for (int c = 0; c < NCH; ++c) o[c] += base[(size_t)c * N];
    }
    const float rd = 1.0f / den;
    float4* o4 = (float4*)(out + (size_t)i * NCH);
    o4[0] = make_float4(fmaf(o[0], rd, 1e-6f), fmaf(o[1], rd, 1e-6f),
                        fmaf(o[2], rd, 1e-6f), fmaf(o[3], rd, 1e-6f));
    o4[1] = make_float4(fmaf(o[4], rd, 1e-6f), fmaf(o[5], rd, 1e-6f),
                        fmaf(o[6], rd, 1e-6f), fmaf(o[7], rd, 1e-6f));
}

// generic fallback: one thread per query over all keys (exact math)
__global__ __launch_bounds__(256) void nw_full(const float* __restrict__ q,
                                               const float* __restrict__ k,
                                               const float* __restrict__ v,
                                               const float* __restrict__ kl,
                                               float* __restrict__ out,
                                               int N, int M) {
    const int i = blockIdx.x * 256 + threadIdx.x;
    if (i >= N) return;
    const float qx = q[i * 3 + 0], qy = q[i * 3 + 1], qz = q[i * 3 + 2];
    const float invL = 1.0f / kl[0];
    float num[NCH];
#pragma unroll
    for (int c = 0; c < NCH; ++c) num[c] = 0.0f;
    float den = 0.0f;
    for (int j = 0; j < M; ++j) {
        float dx = qx - k[j * 3 + 0], dy = qy - k[j * 3 + 1], dz = qz - k[j * 3 + 2];
        float d2 = fmaf(dx, dx, fmaf(dy, dy, dz * dz));
        float wt = nw_weight_exact(__builtin_amdgcn_sqrtf(d2) * invL);
        den += wt;
#pragma unroll
        for (int c = 0; c < NCH; ++c) num[c] = fmaf(wt, v[j * NCH + c], num[c]);
    }
    const float rden = 1.0f / den;
#pragma unroll
    for (int c = 0; c < NCH; ++c) out[i * NCH + c] = fmaf(num[c], rden, 1e-6f);
}

extern "C" void kernel_launch(void* const* d_in, const int* in_sizes, int n_in,
                              void* d_out, int out_size, void* d_ws, size_t ws_size,
                              hipStream_t stream) {
    const float* q  = (const float*)d_in[0];
    const float* k  = (const float*)d_in[1];
    const float* v  = (const float*)d_in[2];
    const float* kl = (const float*)d_in[3];
    float* out = (float*)d_out;

    const int N = in_sizes[0] / 3;   // 8192 queries
    const int M = in_sizes[1] / 3;   // 8192 keys

    const int nsb = (M + KSB - 1) / KSB;
    const size_t need_part = (size_t)nsb * 10 * N * sizeof(float);

    if ((N % QG) == 0 && (M % KSB) == 0 && ws_size >= need_part) {
        float* part = (float*)d_ws;
        dim3 grid(N / QG, nsb);
        nw_main<<<grid, TPB, 0, stream>>>(q, k, v, kl, part, N);
        nw_reduce<<<(N + 255) / 256, 256, 0, stream>>>(part, out, N, nsb);
    } else {
        nw_full<<<(N + 255) / 256, 256, 0, stream>>>(q, k, v, kl, out, N, M);
    }
}

// Round 11
// 40.367 us; speedup vs baseline: 2.2858x; 2.2858x over previous
//
#include <hip/hip_runtime.h>

// NW kernel regression, fused pairwise evaluation.
// queries [N,3] f32, keys [M,3] f32, values [M,8] f32, kernelLen [1] f32
// out [N,8] f32 = (K @ V) / (K @ 1) + 1e-6,
// K[i,j] = max(0, (2+cos(2*pi*d))*(1-d)/3 + sin(2*pi*d)/(2*pi)), d = |q_i-k_j|/L
//
// Round-11 = round-9 skeleton (uniform k/v on the SCALAR path via readfirstlane
// -> s_load; round 10 proved vector loads for uniform data are 2x worse) plus:
//  - 2-key packed inner loop: distance/index math in v_pk_*_f32 (halves that
//    VALU issue); k-pair packing rides the SALU (dual-issue, free)
//  - LUTN 4096 -> 2048: LDS 37.4->28.7 KB -> 5 blocks/CU (40 waves, +25%
//    latency hiding). NN quantization err ~5e-4 -> total absmax ~7e-4 << 2e-3.
//  - deterministic partials in d_ws + reduce kernel

typedef float v2f __attribute__((ext_vector_type(2)));

#define NCH 8
#define QG 64          // queries per block (= lanes per wave)
#define KSB 512        // keys per block
#define TPB 512        // threads per block
#define NWAVE 8
#define KPW (KSB / NWAVE)   // keys per wave = 64
#define LUTN 2048

__device__ __forceinline__ float nw_weight_exact(float cd) {
    float r  = __builtin_amdgcn_fractf(cd);
    float sn = __builtin_amdgcn_sinf(r);
    float cs = __builtin_amdgcn_cosf(r);
    float t  = (1.0f - cd) * (1.0f / 3.0f);
    float wt = fmaf(sn, 0.15915494309189535f, fmaf(cs, t, t + t));
    return fmaxf(wt, 0.0f);
}

__global__ __launch_bounds__(TPB) void nw_main(const float* __restrict__ q,
                                               const float* __restrict__ k,
                                               const float* __restrict__ v,
                                               const float* __restrict__ kl,
                                               float* __restrict__ part,
                                               int N) {
    __shared__ float lutw[LUTN + 1];   // w at s = e/LUTN
    __shared__ float red[TPB * 10];    // cross-wave reduce buffer

    const int tid  = threadIdx.x;
    const int lane = tid & 63;
    const int wid  = tid >> 6;
    const int qg   = blockIdx.x;
    const int sb   = blockIdx.y;

    const float invL = 1.0f / kl[0];

    // ---- build LUT over s in [0,1] (2049 exact evals, amortized) ----
    for (int e = tid; e <= LUTN; e += TPB) {
        float s = (float)e * (1.0f / (float)LUTN);
        lutw[e] = nw_weight_exact(__builtin_amdgcn_sqrtf(s));
    }
    __syncthreads();

    const int i = qg * QG + lane;
    const float qx = q[i * 3 + 0];
    const float qy = q[i * 3 + 1];
    const float qz = q[i * 3 + 2];
    const float scale = invL * invL * (float)LUTN;

    const v2f qxp = {qx, qx}, qyp = {qy, qy}, qzp = {qz, qz};
    const v2f scl2 = {scale, scale};
    const v2f half2 = {0.5f, 0.5f};

    // wave-uniform key base in SGPR -> k/v loads scalarize to s_load
    const int uwid = __builtin_amdgcn_readfirstlane(wid);
    const int jbase = sb * KSB + uwid * KPW;
    const float* __restrict__ kp = k + (size_t)jbase * 3;
    const float* __restrict__ vp = v + (size_t)jbase * 8;

    v2f acc4[4];
#pragma unroll
    for (int c = 0; c < 4; ++c) acc4[c] = v2f{0.0f, 0.0f};
    v2f den2 = {0.0f, 0.0f};

#pragma unroll 4
    for (int jp = 0; jp < KPW / 2; ++jp) {
        const int ja = 2 * jp, jb = 2 * jp + 1;
        // uniform scalar loads (SALU/K$); pair-packing via s_mov (dual-issue)
        const v2f kxp = {kp[ja * 3 + 0], kp[jb * 3 + 0]};
        const v2f kyp = {kp[ja * 3 + 1], kp[jb * 3 + 1]};
        const v2f kzp = {kp[ja * 3 + 2], kp[jb * 3 + 2]};
        const v2f* vva = (const v2f*)(vp + (size_t)ja * 8);
        const v2f* vvb = (const v2f*)(vp + (size_t)jb * 8);

        // packed distance + LUT index for the key pair
        v2f dx = qxp - kxp, dy = qyp - kyp, dz = qzp - kzp;
        v2f d2 = dx * dx;
        d2 += dy * dy;
        d2 += dz * dz;
        v2f fidx = d2 * scl2 + half2;          // v_pk_fma
        float fa = fminf(fidx.x, (float)LUTN);
        float fb = fminf(fidx.y, (float)LUTN);
        float wta = lutw[(int)fa];             // b32 gather (only lgkm-LDS op)
        float wtb = lutw[(int)fb];

        den2 += v2f{wta, wtb};
        v2f wa2 = {wta, wta}, wb2 = {wtb, wtb};
        acc4[0] += wa2 * vva[0];               // v_pk_fma_f32, sgpr-pair src
        acc4[1] += wa2 * vva[1];
        acc4[2] += wa2 * vva[2];
        acc4[3] += wa2 * vva[3];
        acc4[0] += wb2 * vvb[0];
        acc4[1] += wb2 * vvb[1];
        acc4[2] += wb2 * vvb[2];
        acc4[3] += wb2 * vvb[3];
    }
    const float den = den2.x + den2.y;

    __syncthreads();   // LUT phase over; red[] free
    {
        float vals[10] = {acc4[0].x, acc4[0].y, acc4[1].x, acc4[1].y,
                          acc4[2].x, acc4[2].y, acc4[3].x, acc4[3].y, den, 0.0f};
        float* r = red + (size_t)(wid * 64 + lane) * 10;
#pragma unroll
        for (int c = 0; c < 10; ++c) r[c] = vals[c];
    }
    __syncthreads();

    // cross-wave sum: thread (c=wid, l=lane) -> part[sb][c][qg*64+l]
    {
        const int c = wid, l = lane;
        float s = 0.0f;
#pragma unroll
        for (int ww = 0; ww < NWAVE; ++ww) s += red[(size_t)(ww * 64 + l) * 10 + c];
        const int gi = qg * QG + l;
        part[((size_t)sb * 10 + c) * N + gi] = s;
        if (tid < 64) {
            float sd = 0.0f;
#pragma unroll
            for (int ww = 0; ww < NWAVE; ++ww) sd += red[(size_t)(ww * 64 + l) * 10 + 8];
            part[((size_t)sb * 10 + 8) * N + gi] = sd;
        }
    }
}

// out[i,c] = (sum_sb num) / (sum_sb den) + 1e-6; coalesced row reads
__global__ __launch_bounds__(256) void nw_reduce(const float* __restrict__ part,
                                                 float* __restrict__ out,
                                                 int N, int nsb) {
    const int i = blockIdx.x * 256 + threadIdx.x;
    if (i >= N) return;
    float o[NCH];
#pragma unroll
    for (int c = 0; c < NCH; ++c) o[c] = 0.0f;
    float den = 0.0f;
    for (int sb = 0; sb < nsb; ++sb) {
        const float* base = part + (size_t)sb * 10 * N + i;
        den += base[8 * (size_t)N];
#pragma unroll
        for (int c = 0; c < NCH; ++c) o[c] += base[(size_t)c * N];
    }
    const float rd = 1.0f / den;
    float4* o4 = (float4*)(out + (size_t)i * NCH);
    o4[0] = make_float4(fmaf(o[0], rd, 1e-6f), fmaf(o[1], rd, 1e-6f),
                        fmaf(o[2], rd, 1e-6f), fmaf(o[3], rd, 1e-6f));
    o4[1] = make_float4(fmaf(o[4], rd, 1e-6f), fmaf(o[5], rd, 1e-6f),
                        fmaf(o[6], rd, 1e-6f), fmaf(o[7], rd, 1e-6f));
}

// generic fallback: one thread per query over all keys (exact math)
__global__ __launch_bounds__(256) void nw_full(const float* __restrict__ q,
                                               const float* __restrict__ k,
                                               const float* __restrict__ v,
                                               const float* __restrict__ kl,
                                               float* __restrict__ out,
                                               int N, int M) {
    const int i = blockIdx.x * 256 + threadIdx.x;
    if (i >= N) return;
    const float qx = q[i * 3 + 0], qy = q[i * 3 + 1], qz = q[i * 3 + 2];
    const float invL = 1.0f / kl[0];
    float num[NCH];
#pragma unroll
    for (int c = 0; c < NCH; ++c) num[c] = 0.0f;
    float den = 0.0f;
    for (int j = 0; j < M; ++j) {
        float dx = qx - k[j * 3 + 0], dy = qy - k[j * 3 + 1], dz = qz - k[j * 3 + 2];
        float d2 = fmaf(dx, dx, fmaf(dy, dy, dz * dz));
        float wt = nw_weight_exact(__builtin_amdgcn_sqrtf(d2) * invL);
        den += wt;
#pragma unroll
        for (int c = 0; c < NCH; ++c) num[c] = fmaf(wt, v[j * NCH + c], num[c]);
    }
    const float rden = 1.0f / den;
#pragma unroll
    for (int c = 0; c < NCH; ++c) out[i * NCH + c] = fmaf(num[c], rden, 1e-6f);
}

extern "C" void kernel_launch(void* const* d_in, const int* in_sizes, int n_in,
                              void* d_out, int out_size, void* d_ws, size_t ws_size,
                              hipStream_t stream) {
    const float* q  = (const float*)d_in[0];
    const float* k  = (const float*)d_in[1];
    const float* v  = (const float*)d_in[2];
    const float* kl = (const float*)d_in[3];
    float* out = (float*)d_out;

    const int N = in_sizes[0] / 3;   // 8192 queries
    const int M = in_sizes[1] / 3;   // 8192 keys

    const int nsb = (M + KSB - 1) / KSB;
    const size_t need_part = (size_t)nsb * 10 * N * sizeof(float);

    if ((N % QG) == 0 && (M % KSB) == 0 && ws_size >= need_part) {
        float* part = (float*)d_ws;
        dim3 grid(N / QG, nsb);
        nw_main<<<grid, TPB, 0, stream>>>(q, k, v, kl, part, N);
        nw_reduce<<<(N + 255) / 256, 256, 0, stream>>>(part, out, N, nsb);
    } else {
        nw_full<<<(N + 255) / 256, 256, 0, stream>>>(q, k, v, kl, out, N, M);
    }
}